// Round 12
// baseline (1067.746 us; speedup 1.0000x reference)
//
#include <hip/hip_runtime.h>
#include <hip/hip_bf16.h>
#include <math.h>

#define NB 4
#define LIN 40960
#define NC 512
#define T0 8192
#define T1 2048
#define T2 1024
#define T3 512
#define TN 256
#define DM 2048
#define EPSF 1e-5f
#define TEMPF 1e-5f

typedef __attribute__((ext_vector_type(8))) short bf16x8;
typedef __attribute__((ext_vector_type(4))) float f32x4;

__device__ __forceinline__ int refl(int t, int T) {
  if (t < 0) t = -t;
  if (t >= T) t = 2 * T - 2 - t;
  return t;
}

__device__ __forceinline__ void gld16(void* lds, const void* g) {
  __builtin_amdgcn_global_load_lds((const __attribute__((address_space(1))) unsigned int*)g,
                                   (__attribute__((address_space(3))) unsigned int*)lds, 16, 0, 0);
}

__device__ __forceinline__ void blk_sum2_512(float& a, float& b, float* scratch) {
#pragma unroll
  for (int off = 32; off > 0; off >>= 1) {
    a += __shfl_down(a, off, 64);
    b += __shfl_down(b, off, 64);
  }
  int lane = threadIdx.x & 63, wid = threadIdx.x >> 6;
  __syncthreads();
  if (lane == 0) { scratch[wid] = a; scratch[8 + wid] = b; }
  __syncthreads();
  float sa = 0.f, sb = 0.f;
#pragma unroll
  for (int i = 0; i < 8; i++) { sa += scratch[i]; sb += scratch[8 + i]; }
  a = sa; b = sb;
}

// load 8 bf16 (16B) -> 8 floats, accumulate
__device__ __forceinline__ void add_bf8(const __hip_bfloat16* p, float* v) {
  union { uint4 u; __hip_bfloat16 h[8]; } pk;
  pk.u = *(const uint4*)p;
#pragma unroll
  for (int j = 0; j < 8; j++) v[j] += __bfloat162float(pk.h[j]);
}

// ---------------- merged init kernel: conv0 (blocks 0..4095) + weight prep ----------------
template <int KT>
__device__ __forceinline__ void prep_conv_body(const float* __restrict__ w, __hip_bfloat16* __restrict__ wt,
                                               int co, float* l) {
  const float* wb = w + (size_t)co * 512 * KT;
  for (int i = threadIdx.x; i < 512 * KT; i += 512) l[i] = wb[i];
  __syncthreads();
  __hip_bfloat16* wo = wt + (size_t)co * 512 * KT;
  for (int i = threadIdx.x; i < 512 * KT; i += 512) {
    int kk = i >> 9, ci = i & 511;
    wo[i] = __float2bfloat16(l[ci * KT + kk]);
  }
}

template <int KD, int ND>
__device__ __forceinline__ void prep_mlp_body(const float* __restrict__ w, __hip_bfloat16* __restrict__ wt,
                                              int bidx, float* sbuf) {
  float(*tile)[33] = (float(*)[33])sbuf;
  int bx = bidx % (ND / 32);
  int by = bidx / (ND / 32);
  int tx = threadIdx.x & 31, ty = threadIdx.x >> 5;  // ty 0..15
#pragma unroll
  for (int i = 0; i < 32; i += 16)
    tile[ty + i][tx] = w[(size_t)(by * 32 + ty + i) * ND + bx * 32 + tx];
  __syncthreads();
#pragma unroll
  for (int i = 0; i < 32; i += 16)
    wt[(size_t)(bx * 32 + ty + i) * KD + by * 32 + tx] = __float2bfloat16(tile[tx][ty + i]);
}

__device__ __forceinline__ void conv0_body(const float* __restrict__ x, const float* __restrict__ w,
                                           const float* __restrict__ bias, const float* __restrict__ gw,
                                           const float* __restrict__ gb, __hip_bfloat16* __restrict__ out,
                                           int blk, float* smem) {
  float* xv = smem;            // 48
  float* tb = smem + 64;       // 4608
  float* stats = smem + 4672;  // 16
  int b = blk / (T0 / 8);
  int t0 = (blk % (T0 / 8)) * 8;
  int tid = threadIdx.x;
  if (tid < 45) xv[tid] = x[(size_t)b * LIN + refl(t0 * 5 - 3 + tid, LIN)];
  __syncthreads();
  float wk[10];
#pragma unroll
  for (int k = 0; k < 10; k++) wk[k] = w[tid * 10 + k];
  float bs = bias[tid];
  float acc[8];
#pragma unroll
  for (int tt = 0; tt < 8; tt++) {
    float a = bs;
#pragma unroll
    for (int k = 0; k < 10; k++) a += xv[tt * 5 + k] * wk[k];
    acc[tt] = a;
    tb[tid * 9 + tt] = a;
  }
  __syncthreads();
  int wave = tid >> 6, lane = tid & 63;
  float s = 0.f, q = 0.f;
#pragma unroll
  for (int j = 0; j < 8; j++) {
    float v = tb[(lane * 8 + j) * 9 + wave];
    s += v; q += v * v;
  }
#pragma unroll
  for (int off = 32; off > 0; off >>= 1) {
    s += __shfl_xor(s, off, 64);
    q += __shfl_xor(q, off, 64);
  }
  if (lane == 0) {
    float mean = s * (1.f / NC);
    float var = fmaxf((q - s * s * (1.f / NC)) * (1.f / (NC - 1)), 0.f);
    stats[wave] = mean;
    stats[8 + wave] = rsqrtf(var + EPSF);
  }
  __syncthreads();
  float gwv = gw[tid], gbv = gb[tid];
#pragma unroll
  for (int tt = 0; tt < 8; tt++) {
    float y = (acc[tt] - stats[tt]) * stats[8 + tt] * gwv + gbv;
    out[((size_t)(b * T0 + t0 + tt)) * NC + tid] = __float2bfloat16(fmaxf(y, 0.f));
  }
}

// blocks: [0,4096) conv0; then prep: 512 conv1w, 512 conv2w, 512 conv3w, 1024 mlp1w, 4096 mlp2w
__global__ __launch_bounds__(512) void k_init(const float* x, const float* c0w, const float* c0b,
                                              const float* n0w, const float* n0b, __hip_bfloat16* h0b,
                                              const float* c1w, const float* c2w, const float* c3w,
                                              const float* mw1, const float* mw2,
                                              __hip_bfloat16* wt1, __hip_bfloat16* wt2,
                                              __hip_bfloat16* wt3, __hip_bfloat16* wm1t,
                                              __hip_bfloat16* wm2t) {
  __shared__ float smem[4688];
  int b = blockIdx.x;
  if (b < 4096) conv0_body(x, c0w, c0b, n0w, n0b, h0b, b, smem);
  else if (b < 4608) prep_conv_body<8>(c1w, wt1, b - 4096, smem);
  else if (b < 5120) prep_conv_body<4>(c2w, wt2, b - 4608, smem);
  else if (b < 5632) prep_conv_body<4>(c3w, wt3, b - 5120, smem);
  else if (b < 6656) prep_mlp_body<512, 2048>(mw1, wm1t, b - 5632, smem);
  else prep_mlp_body<2048, 2048>(mw2, wm2t, b - 6656, smem);
}

// ---------------- MFMA GEMM v2: 256x128 tile, wave=128x64, BK=32, dbuf, SK, fused finisher
// FIN=1: last block per 256-row group sums SK bf16 partials + conv bias, ChannelNorm+ReLU -> outB.
// FIN=2: last block per 256-row group sums partials + bias + GELU, dot w3, sigmoid -> outF (imp).
template <int MODE, int TIN_, int TOUT_, int SS, int PP, int KK, int NN, int SPLITK, int MM, int FIN>
__global__ __launch_bounds__(256, 2) void k_gemm2(const __hip_bfloat16* __restrict__ A,
                                                  const __hip_bfloat16* __restrict__ Bt,
                                                  __hip_bfloat16* __restrict__ Cp,
                                                  int* __restrict__ cnt,
                                                  const float* __restrict__ f0,
                                                  const float* __restrict__ f1,
                                                  const float* __restrict__ f2,
                                                  __hip_bfloat16* __restrict__ outB,
                                                  float* __restrict__ outF) {
  __shared__ __align__(16) __hip_bfloat16 sA[2][256 * 32];
  __shared__ __align__(16) __hip_bfloat16 sB[2][128 * 32];
  const int tid = threadIdx.x;
  const int lane = tid & 63;
  const int wave = tid >> 6;
  const int wm = wave >> 1, wn = wave & 1;
  constexpr int nt = NN / 128;
  constexpr int PS = (MM / 2048) * nt;
  constexpr int KBT = KK / 32;
  const int blk = blockIdx.x;
  const int xs = blk & 7, sl = blk >> 3;
  const int sk = sl / PS, rem = sl % PS;
  const int rg = (rem / nt) * 8 + xs;  // 256-row group id
  const int row0 = rg * 256;
  const int col0 = (rem % nt) * 128;
  const int kb0 = (sk * KBT) / SPLITK, kb1 = ((sk + 1) * KBT) / SPLITK;
  const int cq = lane >> 4, cl = lane & 15;

  const char* aP[4];
  const char* bP[2];

  auto stage = [&](int kb, int buf) {
    bool recalc = (kb == kb0) || (MODE == 1 && (kb & 15) == 0);
    if (recalc) {
#pragma unroll
      for (int rr = 0; rr < 4; rr++) {
        int c = rr * 256 + tid;
        int m = c >> 2, kc = c & 3;
        int kcs = kc ^ (m & 3);
        size_t ga;
        if (MODE == 0) {
          ga = (size_t)(row0 + m) * KK + kb * 32 + kcs * 8;
        } else {
          int r = row0 + m;
          int bb = r / TOUT_;
          int t = r - bb * TOUT_;
          int k = (kb * 32) >> 9;
          int ci = ((kb * 32) & 511) + kcs * 8;
          int gt = refl(t * SS - PP + k, TIN_);
          ga = (((size_t)(bb * TIN_ + gt)) << 9) + ci;
        }
        aP[rr] = (const char*)(A + ga);
      }
#pragma unroll
      for (int rr = 0; rr < 2; rr++) {
        int c = rr * 256 + tid;
        int n = c >> 2, kc = c & 3;
        int kcs = kc ^ (n & 3);
        bP[rr] = (const char*)(Bt + (size_t)(col0 + n) * KK + kb * 32 + kcs * 8);
      }
    }
#pragma unroll
    for (int rr = 0; rr < 4; rr++) {
      int c = rr * 256 + tid;
      gld16((char*)&sA[buf][0] + c * 16, aP[rr]);
      aP[rr] += 64;
    }
#pragma unroll
    for (int rr = 0; rr < 2; rr++) {
      int c = rr * 256 + tid;
      gld16((char*)&sB[buf][0] + c * 16, bP[rr]);
      bP[rr] += 64;
    }
  };

  f32x4 acc[8][4];
  const f32x4 zz = {0.f, 0.f, 0.f, 0.f};
#pragma unroll
  for (int mi = 0; mi < 8; mi++)
#pragma unroll
    for (int ni = 0; ni < 4; ni++) acc[mi][ni] = zz;

  stage(kb0, 0);
  const int p = cq ^ (cl & 3);
  for (int kb = kb0; kb < kb1; kb++) {
    int cur = (kb - kb0) & 1;
    __syncthreads();
    if (kb + 1 < kb1) stage(kb + 1, cur ^ 1);
    const short* bA = (const short*)&sA[cur][0];
    const short* bB = (const short*)&sB[cur][0];
    bf16x8 af[8], bfr[4];
#pragma unroll
    for (int mi = 0; mi < 8; mi++)
      af[mi] = *(const bf16x8*)(bA + (wm * 128 + mi * 16 + cl) * 32 + p * 8);
#pragma unroll
    for (int ni = 0; ni < 4; ni++)
      bfr[ni] = *(const bf16x8*)(bB + (wn * 64 + ni * 16 + cl) * 32 + p * 8);
#pragma unroll
    for (int mi = 0; mi < 8; mi++)
#pragma unroll
      for (int ni = 0; ni < 4; ni++)
        acc[mi][ni] = __builtin_amdgcn_mfma_f32_16x16x32_bf16(af[mi], bfr[ni], acc[mi][ni], 0, 0, 0);
  }

  // epilogue; C/D: col=lane&15, row=(lane>>4)*4+reg; bf16 partial out
#pragma unroll
  for (int mi = 0; mi < 8; mi++)
#pragma unroll
    for (int ni = 0; ni < 4; ni++)
#pragma unroll
      for (int r2 = 0; r2 < 4; r2++) {
        int row = row0 + wm * 128 + mi * 16 + cq * 4 + r2;
        int col = col0 + wn * 64 + ni * 16 + cl;
        Cp[(size_t)sk * MM * NN + (size_t)row * NN + col] = __float2bfloat16(acc[mi][ni][r2]);
      }

  if constexpr (FIN != 0) {
    __threadfence();  // release partial stores
    __shared__ int lf;
    if (tid == 0) lf = (atomicAdd(cnt + rg, 1) == nt * SPLITK - 1) ? 1 : 0;
    __syncthreads();
    if (!lf) return;
    __threadfence();  // acquire other blocks' partials
    if constexpr (FIN == 1) {
      // ChannelNorm over NN=512 cols; lane covers 8 cols; wave handles one row per pass
      float4 c0 = *(const float4*)(f0 + lane * 8), c1 = *(const float4*)(f0 + lane * 8 + 4);
      float4 w0 = *(const float4*)(f1 + lane * 8), w1 = *(const float4*)(f1 + lane * 8 + 4);
      float4 b0 = *(const float4*)(f2 + lane * 8), b1 = *(const float4*)(f2 + lane * 8 + 4);
      float cbv[8] = {c0.x, c0.y, c0.z, c0.w, c1.x, c1.y, c1.z, c1.w};
      float gwv[8] = {w0.x, w0.y, w0.z, w0.w, w1.x, w1.y, w1.z, w1.w};
      float gbv[8] = {b0.x, b0.y, b0.z, b0.w, b1.x, b1.y, b1.z, b1.w};
      for (int it = 0; it < 64; it++) {
        int row = row0 + it * 4 + wave;
        float v[8];
#pragma unroll
        for (int j = 0; j < 8; j++) v[j] = cbv[j];
#pragma unroll
        for (int s = 0; s < SPLITK; s++)
          add_bf8(Cp + (size_t)s * MM * NN + (size_t)row * NN + lane * 8, v);
        float s1 = 0.f, q = 0.f;
#pragma unroll
        for (int j = 0; j < 8; j++) { s1 += v[j]; q += v[j] * v[j]; }
#pragma unroll
        for (int off = 32; off > 0; off >>= 1) {
          s1 += __shfl_xor(s1, off, 64);
          q += __shfl_xor(q, off, 64);
        }
        float mean = s1 * (1.f / NC);
        float var = fmaxf((q - s1 * s1 * (1.f / NC)) * (1.f / (NC - 1)), 0.f);
        float rstd = rsqrtf(var + EPSF);
        union { __hip_bfloat16 h[8]; uint4 u; } pk;
#pragma unroll
        for (int j = 0; j < 8; j++)
          pk.h[j] = __float2bfloat16(fmaxf((v[j] - mean) * rstd * gwv[j] + gbv[j], 0.f));
        *(uint4*)(outB + (size_t)row * NN + lane * 8) = pk.u;
      }
    } else {  // FIN == 2: head (NN == DM == 2048)
      for (int it = 0; it < 64; it++) {
        int row = row0 + it * 4 + wave;
        float a = 0.f;
#pragma unroll
        for (int gq = 0; gq < 4; gq++) {
          int c = gq * 512 + lane * 8;
          float4 x0 = *(const float4*)(f0 + c), x1 = *(const float4*)(f0 + c + 4);
          float v[8] = {x0.x, x0.y, x0.z, x0.w, x1.x, x1.y, x1.z, x1.w};
#pragma unroll
          for (int s = 0; s < SPLITK; s++)
            add_bf8(Cp + (size_t)s * MM * NN + (size_t)row * NN + c, v);
          float4 y0 = *(const float4*)(f1 + c), y1 = *(const float4*)(f1 + c + 4);
          float wv[8] = {y0.x, y0.y, y0.z, y0.w, y1.x, y1.y, y1.z, y1.w};
#pragma unroll
          for (int j = 0; j < 8; j++) {
            float z = 0.5f * v[j] * (1.f + erff(v[j] * 0.70710678118654752f));
            a += z * wv[j];
          }
        }
#pragma unroll
        for (int off = 32; off > 0; off >>= 1) a += __shfl_down(a, off, 64);
        if (lane == 0) outF[row] = 1.f / (1.f + expf(-(a + f2[0]))) + TEMPF;
      }
    }
  }
}

// ---------------- MFMA GEMM v1: 64x128 tile (conv3 w/ FIN=1, mlp1 w/ EPI=1) ----------
template <int MODE, int TIN_, int TOUT_, int SS, int PP, int KK, int NN, int EPI, int SPLITK, int MM, int FIN>
__global__ __launch_bounds__(256, 4) void k_gemm(const __hip_bfloat16* __restrict__ A,
                                                 const __hip_bfloat16* __restrict__ Bt,
                                                 const float* __restrict__ bias,
                                                 __hip_bfloat16* __restrict__ Cout,
                                                 int* __restrict__ cnt,
                                                 const float* __restrict__ f1,
                                                 const float* __restrict__ f2,
                                                 __hip_bfloat16* __restrict__ outB) {
  __shared__ __align__(16) __hip_bfloat16 sA[2][64 * 32];
  __shared__ __align__(16) __hip_bfloat16 sB[2][128 * 32];
  const int tid = threadIdx.x;
  const int lane = tid & 63;
  const int wave = tid >> 6;
  const int wm = wave >> 1, wn = wave & 1;
  constexpr int nt = NN / 128;
  constexpr int PS = (MM / 512) * nt;
  constexpr int KBT = KK / 32;
  const int blk = blockIdx.x;
  const int xs = blk & 7, sl = blk >> 3;
  const int sk = sl / PS, rem = sl % PS;
  const int rg = (rem / nt) * 8 + xs;  // 64-row group id
  const int row0 = rg * 64;
  const int col0 = (rem % nt) * 128;
  const int kb0 = (sk * KBT) / SPLITK, kb1 = ((sk + 1) * KBT) / SPLITK;
  const int cq = lane >> 4, cl = lane & 15;

  const char* aP;
  const char* bP[2];

  auto stage = [&](int kb, int buf) {
    bool recalc = (kb == kb0) || (MODE == 1 && (kb & 15) == 0);
    if (recalc) {
      {
        int m = tid >> 2, kc = tid & 3;
        int kcs = kc ^ (m & 3);
        size_t ga;
        if (MODE == 0) {
          ga = (size_t)(row0 + m) * KK + kb * 32 + kcs * 8;
        } else {
          int r = row0 + m;
          int bb = r / TOUT_;
          int t = r - bb * TOUT_;
          int k = (kb * 32) >> 9;
          int ci = ((kb * 32) & 511) + kcs * 8;
          int gt = refl(t * SS - PP + k, TIN_);
          ga = (((size_t)(bb * TIN_ + gt)) << 9) + ci;
        }
        aP = (const char*)(A + ga);
      }
#pragma unroll
      for (int rr = 0; rr < 2; rr++) {
        int c = rr * 256 + tid;
        int n = c >> 2, kc = c & 3;
        int kcs = kc ^ (n & 3);
        bP[rr] = (const char*)(Bt + (size_t)(col0 + n) * KK + kb * 32 + kcs * 8);
      }
    }
    gld16((char*)&sA[buf][0] + tid * 16, aP);
    aP += 64;
#pragma unroll
    for (int rr = 0; rr < 2; rr++) {
      int c = rr * 256 + tid;
      gld16((char*)&sB[buf][0] + c * 16, bP[rr]);
      bP[rr] += 64;
    }
  };

  f32x4 acc[2][4];
  const f32x4 zz = {0.f, 0.f, 0.f, 0.f};
#pragma unroll
  for (int mi = 0; mi < 2; mi++)
#pragma unroll
    for (int ni = 0; ni < 4; ni++) acc[mi][ni] = zz;

  stage(kb0, 0);
  const int p = cq ^ (cl & 3);
  for (int kb = kb0; kb < kb1; kb++) {
    int cur = (kb - kb0) & 1;
    __syncthreads();
    if (kb + 1 < kb1) stage(kb + 1, cur ^ 1);
    const short* bA = (const short*)&sA[cur][0];
    const short* bB = (const short*)&sB[cur][0];
    bf16x8 af[2], bfr[4];
#pragma unroll
    for (int mi = 0; mi < 2; mi++)
      af[mi] = *(const bf16x8*)(bA + (wm * 32 + mi * 16 + cl) * 32 + p * 8);
#pragma unroll
    for (int ni = 0; ni < 4; ni++)
      bfr[ni] = *(const bf16x8*)(bB + (wn * 64 + ni * 16 + cl) * 32 + p * 8);
#pragma unroll
    for (int mi = 0; mi < 2; mi++)
#pragma unroll
      for (int ni = 0; ni < 4; ni++)
        acc[mi][ni] = __builtin_amdgcn_mfma_f32_16x16x32_bf16(af[mi], bfr[ni], acc[mi][ni], 0, 0, 0);
  }

#pragma unroll
  for (int mi = 0; mi < 2; mi++)
#pragma unroll
    for (int ni = 0; ni < 4; ni++)
#pragma unroll
      for (int r2 = 0; r2 < 4; r2++) {
        int row = row0 + wm * 32 + mi * 16 + cq * 4 + r2;
        int col = col0 + wn * 64 + ni * 16 + cl;
        float v = acc[mi][ni][r2];
        if (EPI == 1) {
          v += bias[col];
          v = 0.5f * v * (1.f + erff(v * 0.70710678118654752f));
          Cout[(size_t)row * NN + col] = __float2bfloat16(v);
        } else {
          Cout[(size_t)sk * MM * NN + (size_t)row * NN + col] = __float2bfloat16(v);
        }
      }

  if constexpr (FIN == 1) {
    __threadfence();
    __shared__ int lf;
    if (tid == 0) lf = (atomicAdd(cnt + rg, 1) == nt * SPLITK - 1) ? 1 : 0;
    __syncthreads();
    if (!lf) return;
    __threadfence();
    float4 c0 = *(const float4*)(bias + lane * 8), c1 = *(const float4*)(bias + lane * 8 + 4);
    float4 w0 = *(const float4*)(f1 + lane * 8), w1 = *(const float4*)(f1 + lane * 8 + 4);
    float4 b0 = *(const float4*)(f2 + lane * 8), b1 = *(const float4*)(f2 + lane * 8 + 4);
    float cbv[8] = {c0.x, c0.y, c0.z, c0.w, c1.x, c1.y, c1.z, c1.w};
    float gwv[8] = {w0.x, w0.y, w0.z, w0.w, w1.x, w1.y, w1.z, w1.w};
    float gbv[8] = {b0.x, b0.y, b0.z, b0.w, b1.x, b1.y, b1.z, b1.w};
    for (int it = 0; it < 16; it++) {
      int row = row0 + it * 4 + wave;
      float v[8];
#pragma unroll
      for (int j = 0; j < 8; j++) v[j] = cbv[j];
#pragma unroll
      for (int s = 0; s < SPLITK; s++)
        add_bf8(Cout + (size_t)s * MM * NN + (size_t)row * NN + lane * 8, v);
      float s1 = 0.f, q = 0.f;
#pragma unroll
      for (int j = 0; j < 8; j++) { s1 += v[j]; q += v[j] * v[j]; }
#pragma unroll
      for (int off = 32; off > 0; off >>= 1) {
        s1 += __shfl_xor(s1, off, 64);
        q += __shfl_xor(q, off, 64);
      }
      float mean = s1 * (1.f / NC);
      float var = fmaxf((q - s1 * s1 * (1.f / NC)) * (1.f / (NC - 1)), 0.f);
      float rstd = rsqrtf(var + EPSF);
      union { __hip_bfloat16 h[8]; uint4 u; } pk;
#pragma unroll
      for (int j = 0; j < 8; j++)
        pk.h[j] = __float2bfloat16(fmaxf((v[j] - mean) * rstd * gwv[j] + gbv[j], 0.f));
      *(uint4*)(outB + (size_t)row * NN + lane * 8) = pk.u;
    }
  }
}

__device__ __forceinline__ float dfun(float cv, int n) {
  float d = fmaxf(cv - (float)n, 0.f);
  if (n < TN - 1) d = fminf(d, 1.f);
  return d;
}

// ---------------- fused cumsum + pool + final ChannelNorm + ReLU, write [B][C][TN] ----
__global__ __launch_bounds__(512) void k_poolfinal(const __hip_bfloat16* __restrict__ f,
                                                   const float* __restrict__ imp,
                                                   const float* __restrict__ gw, const float* __restrict__ gb,
                                                   float* __restrict__ out) {
  __shared__ float wt[T3];
  __shared__ float wsum[8];
  __shared__ float red[16];
  int b = blockIdx.x / TN, n = blockIdx.x % TN;
  int tid = threadIdx.x, wave = tid >> 6, lane = tid & 63;
  float own = imp[b * T3 + tid];
  float s = own;
#pragma unroll
  for (int off = 1; off < 64; off <<= 1) {
    float t = __shfl_up(s, off, 64);
    if (lane >= off) s += t;
  }
  if (lane == 63) wsum[wave] = s;
  __syncthreads();
  float prefix = 0.f, total = 0.f;
#pragma unroll
  for (int w = 0; w < 8; w++) {
    float ws_ = wsum[w];
    total += ws_;
    if (w < wave) prefix += ws_;
  }
  float scale = (float)TN / total;
  float incl = (prefix + s) * scale;
  float excl = (prefix + s - own) * scale;
  wt[tid] = dfun(incl, n) - dfun(excl, n);
  __syncthreads();
  float acc = 0.f;
  for (int t = 0; t < T3; t++) {
    float w = wt[t];
    if (w != 0.f) acc += w * __bfloat162float(f[((size_t)b * T3 + t) * NC + tid]);
  }
  float sv = acc, q = acc * acc;
  blk_sum2_512(sv, q, red);
  float mean = sv * (1.f / NC);
  float var = fmaxf((q - sv * sv * (1.f / NC)) * (1.f / (NC - 1)), 0.f);
  float y = (acc - mean) * rsqrtf(var + EPSF) * gw[tid] + gb[tid];
  out[((size_t)b * NC + tid) * TN + n] = fmaxf(y, 0.f);
}

extern "C" void kernel_launch(void* const* d_in, const int* in_sizes, int n_in,
                              void* d_out, int out_size, void* d_ws, size_t ws_size,
                              hipStream_t stream) {
  const float* x   = (const float*)d_in[0];
  const float* c0w = (const float*)d_in[1];  const float* c0b = (const float*)d_in[2];
  const float* c1w = (const float*)d_in[3];  const float* c1b = (const float*)d_in[4];
  const float* c2w = (const float*)d_in[5];  const float* c2b = (const float*)d_in[6];
  const float* c3w = (const float*)d_in[7];  const float* c3b = (const float*)d_in[8];
  const float* mw1 = (const float*)d_in[9];  const float* mb1 = (const float*)d_in[10];
  const float* mw2 = (const float*)d_in[11]; const float* mb2 = (const float*)d_in[12];
  const float* mw3 = (const float*)d_in[13]; const float* mb3 = (const float*)d_in[14];
  const float* n0w = (const float*)d_in[15]; const float* n0b = (const float*)d_in[16];
  const float* n1w = (const float*)d_in[17]; const float* n1b = (const float*)d_in[18];
  const float* n2w = (const float*)d_in[19]; const float* n2b = (const float*)d_in[20];
  const float* n3w = (const float*)d_in[21]; const float* n3b = (const float*)d_in[22];
  const float* n4w = (const float*)d_in[23]; const float* n4b = (const float*)d_in[24];

  char* base = (char*)d_ws;
  // Workspace map (MiB). Peak 90 MiB + 512 B (<= 97 MiB proven safe in R4/R5).
  __hip_bfloat16* h0b  = (__hip_bfloat16*)(base);                     // [0,32): conv0 out
  __hip_bfloat16* g    = (__hip_bfloat16*)(base + (32u << 20));       // [32,64): bf16 split-K partials
  __hip_bfloat16* wm1t = (__hip_bfloat16*)(base + (64u << 20));       // [64,66)
  __hip_bfloat16* wt2  = (__hip_bfloat16*)(base + (66u << 20));       // [66,68)
  __hip_bfloat16* wt3  = (__hip_bfloat16*)(base + (68u << 20));       // [68,70)
  __hip_bfloat16* wt1  = (__hip_bfloat16*)(base + (70u << 20));       // [70,74)
  __hip_bfloat16* wm2t = (__hip_bfloat16*)(base + (74u << 20));       // [74,82)
  __hip_bfloat16* h1b  = (__hip_bfloat16*)(base + (82u << 20));       // [82,90): NOT aliasing h0b
  int*            cnt  = (int*)(base + (90u << 20));                  // [90,+512B): finisher counters
  __hip_bfloat16* h2b  = (__hip_bfloat16*)(base);                     // [0,4) reuse (h0b dead)
  __hip_bfloat16* h3b  = (__hip_bfloat16*)(base + (4u << 20));        // [4,6)
  __hip_bfloat16* z1b  = (__hip_bfloat16*)(base + (6u << 20));        // [6,14)
  float*          imp  = (float*)(base + (14u << 20));                // [14,+8K)
  float* outp = (float*)d_out;

  hipMemsetAsync(cnt, 0, 512, stream);
  k_init<<<4096 + 6656, 512, 0, stream>>>(x, c0w, c0b, n0w, n0b, h0b,
                                          c1w, c2w, c3w, mw1, mw2, wt1, wt2, wt3, wm1t, wm2t);

  // conv1: M=8192, K=4096, SK4 -> 512 blocks; finisher = cnorm1 -> h1b. 32 groups @ cnt+0.
  k_gemm2<1, 8192, 2048, 4, 2, 4096, 512, 4, 8192, 1><<<512, 256, 0, stream>>>(
      h0b, wt1, g, cnt + 0, c1b, n1w, n1b, h1b, nullptr);
  // conv2: M=4096, K=2048, SK8 -> 512 blocks; finisher = cnorm2 -> h2b. 16 groups @ cnt+32.
  k_gemm2<1, 2048, 1024, 2, 1, 2048, 512, 8, 4096, 1><<<512, 256, 0, stream>>>(
      h1b, wt2, g, cnt + 32, c2b, n2w, n2b, h2b, nullptr);
  // conv3: M=2048, K=2048, 64x128, SK8 -> 1024 blocks; finisher = cnorm3 -> h3b. 32 groups @ cnt+48.
  k_gemm<1, 1024, 512, 2, 1, 2048, 512, 0, 8, 2048, 1><<<1024, 256, 0, stream>>>(
      h2b, wt3, c3b, g, cnt + 48, n3w, n3b, h3b);
  // mlp1: M=2048, K=512, EPI=GELU -> 512 blocks (no finisher).
  k_gemm<0, 0, 1, 0, 0, 512, 2048, 1, 1, 2048, 0><<<512, 256, 0, stream>>>(
      h3b, wm1t, mb1, z1b, nullptr, nullptr, nullptr, nullptr);
  // mlp2: M=2048, K=2048, N=2048, SK4 -> 512 blocks; finisher = head -> imp. 8 groups @ cnt+80.
  k_gemm2<0, 0, 1, 0, 0, 2048, 2048, 4, 2048, 2><<<512, 256, 0, stream>>>(
      z1b, wm2t, g, cnt + 80, mb2, mw3, mb3, nullptr, imp);

  k_poolfinal<<<NB * TN, 512, 0, stream>>>(h3b, imp, n4w, n4b, outp);
}

// Round 13
// 317.208 us; speedup vs baseline: 3.3661x; 3.3661x over previous
//
#include <hip/hip_runtime.h>
#include <hip/hip_bf16.h>
#include <math.h>

#define NB 4
#define LIN 40960
#define NC 512
#define T0 8192
#define T1 2048
#define T2 1024
#define T3 512
#define TN 256
#define DM 2048
#define EPSF 1e-5f
#define TEMPF 1e-5f

typedef __attribute__((ext_vector_type(8))) short bf16x8;
typedef __attribute__((ext_vector_type(4))) float f32x4;

__device__ __forceinline__ int refl(int t, int T) {
  if (t < 0) t = -t;
  if (t >= T) t = 2 * T - 2 - t;
  return t;
}

__device__ __forceinline__ void gld16(void* lds, const void* g) {
  __builtin_amdgcn_global_load_lds((const __attribute__((address_space(1))) unsigned int*)g,
                                   (__attribute__((address_space(3))) unsigned int*)lds, 16, 0, 0);
}

__device__ __forceinline__ void blk_sum2_512(float& a, float& b, float* scratch) {
#pragma unroll
  for (int off = 32; off > 0; off >>= 1) {
    a += __shfl_down(a, off, 64);
    b += __shfl_down(b, off, 64);
  }
  int lane = threadIdx.x & 63, wid = threadIdx.x >> 6;
  __syncthreads();
  if (lane == 0) { scratch[wid] = a; scratch[8 + wid] = b; }
  __syncthreads();
  float sa = 0.f, sb = 0.f;
#pragma unroll
  for (int i = 0; i < 8; i++) { sa += scratch[i]; sb += scratch[8 + i]; }
  a = sa; b = sb;
}

__device__ __forceinline__ void add_bf8(const __hip_bfloat16* p, float* v) {
  union { uint4 u; __hip_bfloat16 h[8]; } pk;
  pk.u = *(const uint4*)p;
#pragma unroll
  for (int j = 0; j < 8; j++) v[j] += __bfloat162float(pk.h[j]);
}

// ---------------- merged init: conv0 (blocks 0..4095) + weight prep ----------------
template <int KT>
__device__ __forceinline__ void prep_conv_body(const float* __restrict__ w, __hip_bfloat16* __restrict__ wt,
                                               int co, float* l) {
  const float* wb = w + (size_t)co * 512 * KT;
  for (int i = threadIdx.x; i < 512 * KT; i += 512) l[i] = wb[i];
  __syncthreads();
  __hip_bfloat16* wo = wt + (size_t)co * 512 * KT;
  for (int i = threadIdx.x; i < 512 * KT; i += 512) {
    int kk = i >> 9, ci = i & 511;
    wo[i] = __float2bfloat16(l[ci * KT + kk]);
  }
}

template <int KD, int ND>
__device__ __forceinline__ void prep_mlp_body(const float* __restrict__ w, __hip_bfloat16* __restrict__ wt,
                                              int bidx, float* sbuf) {
  float(*tile)[33] = (float(*)[33])sbuf;
  int bx = bidx % (ND / 32);
  int by = bidx / (ND / 32);
  int tx = threadIdx.x & 31, ty = threadIdx.x >> 5;  // ty 0..15
#pragma unroll
  for (int i = 0; i < 32; i += 16)
    tile[ty + i][tx] = w[(size_t)(by * 32 + ty + i) * ND + bx * 32 + tx];
  __syncthreads();
#pragma unroll
  for (int i = 0; i < 32; i += 16)
    wt[(size_t)(bx * 32 + ty + i) * KD + by * 32 + tx] = __float2bfloat16(tile[tx][ty + i]);
}

__device__ __forceinline__ void conv0_body(const float* __restrict__ x, const float* __restrict__ w,
                                           const float* __restrict__ bias, const float* __restrict__ gw,
                                           const float* __restrict__ gb, __hip_bfloat16* __restrict__ out,
                                           int blk, float* smem) {
  float* xv = smem;
  float* tb = smem + 64;
  float* stats = smem + 4672;
  int b = blk / (T0 / 8);
  int t0 = (blk % (T0 / 8)) * 8;
  int tid = threadIdx.x;
  if (tid < 45) xv[tid] = x[(size_t)b * LIN + refl(t0 * 5 - 3 + tid, LIN)];
  __syncthreads();
  float wk[10];
#pragma unroll
  for (int k = 0; k < 10; k++) wk[k] = w[tid * 10 + k];
  float bs = bias[tid];
  float acc[8];
#pragma unroll
  for (int tt = 0; tt < 8; tt++) {
    float a = bs;
#pragma unroll
    for (int k = 0; k < 10; k++) a += xv[tt * 5 + k] * wk[k];
    acc[tt] = a;
    tb[tid * 9 + tt] = a;
  }
  __syncthreads();
  int wave = tid >> 6, lane = tid & 63;
  float s = 0.f, q = 0.f;
#pragma unroll
  for (int j = 0; j < 8; j++) {
    float v = tb[(lane * 8 + j) * 9 + wave];
    s += v; q += v * v;
  }
#pragma unroll
  for (int off = 32; off > 0; off >>= 1) {
    s += __shfl_xor(s, off, 64);
    q += __shfl_xor(q, off, 64);
  }
  if (lane == 0) {
    float mean = s * (1.f / NC);
    float var = fmaxf((q - s * s * (1.f / NC)) * (1.f / (NC - 1)), 0.f);
    stats[wave] = mean;
    stats[8 + wave] = rsqrtf(var + EPSF);
  }
  __syncthreads();
  float gwv = gw[tid], gbv = gb[tid];
#pragma unroll
  for (int tt = 0; tt < 8; tt++) {
    float y = (acc[tt] - stats[tt]) * stats[8 + tt] * gwv + gbv;
    out[((size_t)(b * T0 + t0 + tt)) * NC + tid] = __float2bfloat16(fmaxf(y, 0.f));
  }
}

__global__ __launch_bounds__(512) void k_init(const float* x, const float* c0w, const float* c0b,
                                              const float* n0w, const float* n0b, __hip_bfloat16* h0b,
                                              const float* c1w, const float* c2w, const float* c3w,
                                              const float* mw1, const float* mw2,
                                              __hip_bfloat16* wt1, __hip_bfloat16* wt2,
                                              __hip_bfloat16* wt3, __hip_bfloat16* wm1t,
                                              __hip_bfloat16* wm2t) {
  __shared__ float smem[4688];
  int b = blockIdx.x;
  if (b < 4096) conv0_body(x, c0w, c0b, n0w, n0b, h0b, b, smem);
  else if (b < 4608) prep_conv_body<8>(c1w, wt1, b - 4096, smem);
  else if (b < 5120) prep_conv_body<4>(c2w, wt2, b - 4608, smem);
  else if (b < 5632) prep_conv_body<4>(c3w, wt3, b - 5120, smem);
  else if (b < 6656) prep_mlp_body<512, 2048>(mw1, wm1t, b - 5632, smem);
  else prep_mlp_body<2048, 2048>(mw2, wm2t, b - 6656, smem);
}

// ---------------- GEMM A: 256x128 tile (wave=128x64), BK=32, dbuf, SK, strength-reduced ----
// For conv1. 2 blocks/CU; grid must be 512.
template <int MODE, int TIN_, int TOUT_, int SS, int PP, int KK, int NN, int SPLITK, int MM>
__global__ __launch_bounds__(256, 2) void k_gemmA(const __hip_bfloat16* __restrict__ A,
                                                  const __hip_bfloat16* __restrict__ Bt,
                                                  __hip_bfloat16* __restrict__ Cp) {
  __shared__ __align__(16) __hip_bfloat16 sA[2][256 * 32];
  __shared__ __align__(16) __hip_bfloat16 sB[2][128 * 32];
  const int tid = threadIdx.x;
  const int lane = tid & 63;
  const int wave = tid >> 6;
  const int wm = wave >> 1, wn = wave & 1;
  constexpr int nt = NN / 128;
  constexpr int PS = (MM / 2048) * nt;
  constexpr int KBT = KK / 32;
  const int blk = blockIdx.x;
  const int xs = blk & 7, sl = blk >> 3;
  const int sk = sl / PS, rem = sl % PS;
  const int row0 = ((rem / nt) * 8 + xs) * 256;
  const int col0 = (rem % nt) * 128;
  const int kb0 = (sk * KBT) / SPLITK, kb1 = ((sk + 1) * KBT) / SPLITK;
  const int cq = lane >> 4, cl = lane & 15;

  const char* aP[4];
  const char* bP[2];

  auto stage = [&](int kb, int buf) {
    bool recalc = (kb == kb0) || (MODE == 1 && (kb & 15) == 0);
    if (recalc) {
#pragma unroll
      for (int rr = 0; rr < 4; rr++) {
        int c = rr * 256 + tid;
        int m = c >> 2, kc = c & 3;
        int kcs = kc ^ (m & 3);
        size_t ga;
        if (MODE == 0) {
          ga = (size_t)(row0 + m) * KK + kb * 32 + kcs * 8;
        } else {
          int r = row0 + m;
          int bb = r / TOUT_;
          int t = r - bb * TOUT_;
          int k = (kb * 32) >> 9;
          int ci = ((kb * 32) & 511) + kcs * 8;
          int gt = refl(t * SS - PP + k, TIN_);
          ga = (((size_t)(bb * TIN_ + gt)) << 9) + ci;
        }
        aP[rr] = (const char*)(A + ga);
      }
#pragma unroll
      for (int rr = 0; rr < 2; rr++) {
        int c = rr * 256 + tid;
        int n = c >> 2, kc = c & 3;
        int kcs = kc ^ (n & 3);
        bP[rr] = (const char*)(Bt + (size_t)(col0 + n) * KK + kb * 32 + kcs * 8);
      }
    }
#pragma unroll
    for (int rr = 0; rr < 4; rr++) {
      gld16((char*)&sA[buf][0] + (rr * 256 + tid) * 16, aP[rr]);
      aP[rr] += 64;
    }
#pragma unroll
    for (int rr = 0; rr < 2; rr++) {
      gld16((char*)&sB[buf][0] + (rr * 256 + tid) * 16, bP[rr]);
      bP[rr] += 64;
    }
  };

  f32x4 acc[8][4];
  const f32x4 zz = {0.f, 0.f, 0.f, 0.f};
#pragma unroll
  for (int mi = 0; mi < 8; mi++)
#pragma unroll
    for (int ni = 0; ni < 4; ni++) acc[mi][ni] = zz;

  stage(kb0, 0);
  const int p = cq ^ (cl & 3);
  for (int kb = kb0; kb < kb1; kb++) {
    int cur = (kb - kb0) & 1;
    __syncthreads();
    if (kb + 1 < kb1) stage(kb + 1, cur ^ 1);
    const short* bA = (const short*)&sA[cur][0];
    const short* bB = (const short*)&sB[cur][0];
    bf16x8 af[8], bfr[4];
#pragma unroll
    for (int mi = 0; mi < 8; mi++)
      af[mi] = *(const bf16x8*)(bA + (wm * 128 + mi * 16 + cl) * 32 + p * 8);
#pragma unroll
    for (int ni = 0; ni < 4; ni++)
      bfr[ni] = *(const bf16x8*)(bB + (wn * 64 + ni * 16 + cl) * 32 + p * 8);
#pragma unroll
    for (int mi = 0; mi < 8; mi++)
#pragma unroll
      for (int ni = 0; ni < 4; ni++)
        acc[mi][ni] = __builtin_amdgcn_mfma_f32_16x16x32_bf16(af[mi], bfr[ni], acc[mi][ni], 0, 0, 0);
  }

#pragma unroll
  for (int mi = 0; mi < 8; mi++)
#pragma unroll
    for (int ni = 0; ni < 4; ni++)
#pragma unroll
      for (int r2 = 0; r2 < 4; r2++) {
        int row = row0 + wm * 128 + mi * 16 + cq * 4 + r2;
        int col = col0 + wn * 64 + ni * 16 + cl;
        Cp[(size_t)sk * MM * NN + (size_t)row * NN + col] = __float2bfloat16(acc[mi][ni][r2]);
      }
}

// ---------------- GEMM B: 128x128 tile (wave=64x64), BK=32, dbuf, SK, strength-reduced ----
// For conv2/mlp2. ~3 blocks/CU; grids of 768.
template <int MODE, int TIN_, int TOUT_, int SS, int PP, int KK, int NN, int SPLITK, int MM>
__global__ __launch_bounds__(256) void k_gemmB(const __hip_bfloat16* __restrict__ A,
                                               const __hip_bfloat16* __restrict__ Bt,
                                               __hip_bfloat16* __restrict__ Cp) {
  __shared__ __align__(16) __hip_bfloat16 sA[2][128 * 32];
  __shared__ __align__(16) __hip_bfloat16 sB[2][128 * 32];
  const int tid = threadIdx.x;
  const int lane = tid & 63;
  const int wave = tid >> 6;
  const int wm = wave >> 1, wn = wave & 1;
  constexpr int nt = NN / 128;
  constexpr int PS = (MM / 1024) * nt;
  constexpr int KBT = KK / 32;
  const int blk = blockIdx.x;
  const int xs = blk & 7, sl = blk >> 3;
  const int sk = sl / PS, rem = sl % PS;
  const int row0 = ((rem / nt) * 8 + xs) * 128;
  const int col0 = (rem % nt) * 128;
  const int kb0 = (sk * KBT) / SPLITK, kb1 = ((sk + 1) * KBT) / SPLITK;
  const int cq = lane >> 4, cl = lane & 15;

  const char* aP[2];
  const char* bP[2];

  auto stage = [&](int kb, int buf) {
    bool recalc = (kb == kb0) || (MODE == 1 && (kb & 15) == 0);
    if (recalc) {
#pragma unroll
      for (int rr = 0; rr < 2; rr++) {
        int c = rr * 256 + tid;
        int m = c >> 2, kc = c & 3;
        int kcs = kc ^ (m & 3);
        size_t ga;
        if (MODE == 0) {
          ga = (size_t)(row0 + m) * KK + kb * 32 + kcs * 8;
        } else {
          int r = row0 + m;
          int bb = r / TOUT_;
          int t = r - bb * TOUT_;
          int k = (kb * 32) >> 9;
          int ci = ((kb * 32) & 511) + kcs * 8;
          int gt = refl(t * SS - PP + k, TIN_);
          ga = (((size_t)(bb * TIN_ + gt)) << 9) + ci;
        }
        aP[rr] = (const char*)(A + ga);
      }
#pragma unroll
      for (int rr = 0; rr < 2; rr++) {
        int c = rr * 256 + tid;
        int n = c >> 2, kc = c & 3;
        int kcs = kc ^ (n & 3);
        bP[rr] = (const char*)(Bt + (size_t)(col0 + n) * KK + kb * 32 + kcs * 8);
      }
    }
#pragma unroll
    for (int rr = 0; rr < 2; rr++) {
      gld16((char*)&sA[buf][0] + (rr * 256 + tid) * 16, aP[rr]);
      aP[rr] += 64;
    }
#pragma unroll
    for (int rr = 0; rr < 2; rr++) {
      gld16((char*)&sB[buf][0] + (rr * 256 + tid) * 16, bP[rr]);
      bP[rr] += 64;
    }
  };

  f32x4 acc[4][4];
  const f32x4 zz = {0.f, 0.f, 0.f, 0.f};
#pragma unroll
  for (int mi = 0; mi < 4; mi++)
#pragma unroll
    for (int ni = 0; ni < 4; ni++) acc[mi][ni] = zz;

  stage(kb0, 0);
  const int p = cq ^ (cl & 3);
  for (int kb = kb0; kb < kb1; kb++) {
    int cur = (kb - kb0) & 1;
    __syncthreads();
    if (kb + 1 < kb1) stage(kb + 1, cur ^ 1);
    const short* bA = (const short*)&sA[cur][0];
    const short* bB = (const short*)&sB[cur][0];
    bf16x8 af[4], bfr[4];
#pragma unroll
    for (int mi = 0; mi < 4; mi++)
      af[mi] = *(const bf16x8*)(bA + (wm * 64 + mi * 16 + cl) * 32 + p * 8);
#pragma unroll
    for (int ni = 0; ni < 4; ni++)
      bfr[ni] = *(const bf16x8*)(bB + (wn * 64 + ni * 16 + cl) * 32 + p * 8);
#pragma unroll
    for (int mi = 0; mi < 4; mi++)
#pragma unroll
      for (int ni = 0; ni < 4; ni++)
        acc[mi][ni] = __builtin_amdgcn_mfma_f32_16x16x32_bf16(af[mi], bfr[ni], acc[mi][ni], 0, 0, 0);
  }

#pragma unroll
  for (int mi = 0; mi < 4; mi++)
#pragma unroll
    for (int ni = 0; ni < 4; ni++)
#pragma unroll
      for (int r2 = 0; r2 < 4; r2++) {
        int row = row0 + wm * 64 + mi * 16 + cq * 4 + r2;
        int col = col0 + wn * 64 + ni * 16 + cl;
        Cp[(size_t)sk * MM * NN + (size_t)row * NN + col] = __float2bfloat16(acc[mi][ni][r2]);
      }
}

// ---------------- GEMM C: 64x128 tile (conv3, mlp1), strength-reduced ----------
template <int MODE, int TIN_, int TOUT_, int SS, int PP, int KK, int NN, int EPI, int SPLITK, int MM>
__global__ __launch_bounds__(256, 4) void k_gemmC(const __hip_bfloat16* __restrict__ A,
                                                  const __hip_bfloat16* __restrict__ Bt,
                                                  const float* __restrict__ bias,
                                                  __hip_bfloat16* __restrict__ Cout) {
  __shared__ __align__(16) __hip_bfloat16 sA[2][64 * 32];
  __shared__ __align__(16) __hip_bfloat16 sB[2][128 * 32];
  const int tid = threadIdx.x;
  const int lane = tid & 63;
  const int wave = tid >> 6;
  const int wm = wave >> 1, wn = wave & 1;
  constexpr int nt = NN / 128;
  constexpr int PS = (MM / 512) * nt;
  constexpr int KBT = KK / 32;
  const int blk = blockIdx.x;
  const int xs = blk & 7, sl = blk >> 3;
  const int sk = sl / PS, rem = sl % PS;
  const int row0 = ((rem / nt) * 8 + xs) * 64;
  const int col0 = (rem % nt) * 128;
  const int kb0 = (sk * KBT) / SPLITK, kb1 = ((sk + 1) * KBT) / SPLITK;
  const int cq = lane >> 4, cl = lane & 15;

  const char* aP;
  const char* bP[2];

  auto stage = [&](int kb, int buf) {
    bool recalc = (kb == kb0) || (MODE == 1 && (kb & 15) == 0);
    if (recalc) {
      {
        int m = tid >> 2, kc = tid & 3;
        int kcs = kc ^ (m & 3);
        size_t ga;
        if (MODE == 0) {
          ga = (size_t)(row0 + m) * KK + kb * 32 + kcs * 8;
        } else {
          int r = row0 + m;
          int bb = r / TOUT_;
          int t = r - bb * TOUT_;
          int k = (kb * 32) >> 9;
          int ci = ((kb * 32) & 511) + kcs * 8;
          int gt = refl(t * SS - PP + k, TIN_);
          ga = (((size_t)(bb * TIN_ + gt)) << 9) + ci;
        }
        aP = (const char*)(A + ga);
      }
#pragma unroll
      for (int rr = 0; rr < 2; rr++) {
        int c = rr * 256 + tid;
        int n = c >> 2, kc = c & 3;
        int kcs = kc ^ (n & 3);
        bP[rr] = (const char*)(Bt + (size_t)(col0 + n) * KK + kb * 32 + kcs * 8);
      }
    }
    gld16((char*)&sA[buf][0] + tid * 16, aP);
    aP += 64;
#pragma unroll
    for (int rr = 0; rr < 2; rr++) {
      gld16((char*)&sB[buf][0] + (rr * 256 + tid) * 16, bP[rr]);
      bP[rr] += 64;
    }
  };

  f32x4 acc[2][4];
  const f32x4 zz = {0.f, 0.f, 0.f, 0.f};
#pragma unroll
  for (int mi = 0; mi < 2; mi++)
#pragma unroll
    for (int ni = 0; ni < 4; ni++) acc[mi][ni] = zz;

  stage(kb0, 0);
  const int p = cq ^ (cl & 3);
  for (int kb = kb0; kb < kb1; kb++) {
    int cur = (kb - kb0) & 1;
    __syncthreads();
    if (kb + 1 < kb1) stage(kb + 1, cur ^ 1);
    const short* bA = (const short*)&sA[cur][0];
    const short* bB = (const short*)&sB[cur][0];
    bf16x8 af[2], bfr[4];
#pragma unroll
    for (int mi = 0; mi < 2; mi++)
      af[mi] = *(const bf16x8*)(bA + (wm * 32 + mi * 16 + cl) * 32 + p * 8);
#pragma unroll
    for (int ni = 0; ni < 4; ni++)
      bfr[ni] = *(const bf16x8*)(bB + (wn * 64 + ni * 16 + cl) * 32 + p * 8);
#pragma unroll
    for (int mi = 0; mi < 2; mi++)
#pragma unroll
      for (int ni = 0; ni < 4; ni++)
        acc[mi][ni] = __builtin_amdgcn_mfma_f32_16x16x32_bf16(af[mi], bfr[ni], acc[mi][ni], 0, 0, 0);
  }

#pragma unroll
  for (int mi = 0; mi < 2; mi++)
#pragma unroll
    for (int ni = 0; ni < 4; ni++)
#pragma unroll
      for (int r2 = 0; r2 < 4; r2++) {
        int row = row0 + wm * 32 + mi * 16 + cq * 4 + r2;
        int col = col0 + wn * 64 + ni * 16 + cl;
        float v = acc[mi][ni][r2];
        if (EPI == 1) {
          v += bias[col];
          v = 0.5f * v * (1.f + erff(v * 0.70710678118654752f));
          Cout[(size_t)row * NN + col] = __float2bfloat16(v);
        } else {
          Cout[(size_t)sk * MM * NN + (size_t)row * NN + col] = __float2bfloat16(v);
        }
      }
}

// ---------------- ChannelNorm (+conv bias, sum NS bf16 split-K partials) + ReLU -> bf16
template <int NS>
__global__ __launch_bounds__(512) void k_cnorm(const __hip_bfloat16* __restrict__ g,
                                               const float* __restrict__ cb,
                                               const float* __restrict__ gw, const float* __restrict__ gb,
                                               __hip_bfloat16* __restrict__ out, size_t stride) {
  int wave = threadIdx.x >> 6, lane = threadIdx.x & 63;
  size_t row = (size_t)blockIdx.x * 8 + wave;
  float v[8];
  {
    float4 c0 = *(const float4*)(cb + lane * 8), c1 = *(const float4*)(cb + lane * 8 + 4);
    v[0] = c0.x; v[1] = c0.y; v[2] = c0.z; v[3] = c0.w;
    v[4] = c1.x; v[5] = c1.y; v[6] = c1.z; v[7] = c1.w;
  }
#pragma unroll
  for (int s = 0; s < NS; s++) add_bf8(g + s * stride + row * NC + lane * 8, v);
  float s = 0.f, q = 0.f;
#pragma unroll
  for (int j = 0; j < 8; j++) { s += v[j]; q += v[j] * v[j]; }
#pragma unroll
  for (int off = 32; off > 0; off >>= 1) {
    s += __shfl_xor(s, off, 64);
    q += __shfl_xor(q, off, 64);
  }
  float mean = s * (1.f / NC);
  float var = fmaxf((q - s * s * (1.f / NC)) * (1.f / (NC - 1)), 0.f);
  float rstd = rsqrtf(var + EPSF);
  float4 w0 = *(const float4*)(gw + lane * 8), w1 = *(const float4*)(gw + lane * 8 + 4);
  float4 b0 = *(const float4*)(gb + lane * 8), b1 = *(const float4*)(gb + lane * 8 + 4);
  float gwv[8] = {w0.x, w0.y, w0.z, w0.w, w1.x, w1.y, w1.z, w1.w};
  float gbv[8] = {b0.x, b0.y, b0.z, b0.w, b1.x, b1.y, b1.z, b1.w};
  union { __hip_bfloat16 h[8]; uint4 u; } pk;
#pragma unroll
  for (int j = 0; j < 8; j++)
    pk.h[j] = __float2bfloat16(fmaxf((v[j] - mean) * rstd * gwv[j] + gbv[j], 0.f));
  *(uint4*)(out + row * NC + lane * 8) = pk.u;
}

// ---------------- fused head: sum NS bf16 partials + bias + GELU, dot w3, sigmoid ----
template <int NS>
__global__ __launch_bounds__(256) void k_head(const __hip_bfloat16* __restrict__ g,
                                              const float* __restrict__ b2,
                                              const float* __restrict__ w3, const float* __restrict__ b3,
                                              float* __restrict__ imp) {
  __shared__ float red[4];
  int row = blockIdx.x, tid = threadIdx.x;
  int c = tid * 8;
  float v[8];
  {
    float4 x0 = *(const float4*)(b2 + c), x1 = *(const float4*)(b2 + c + 4);
    v[0] = x0.x; v[1] = x0.y; v[2] = x0.z; v[3] = x0.w;
    v[4] = x1.x; v[5] = x1.y; v[6] = x1.z; v[7] = x1.w;
  }
#pragma unroll
  for (int s = 0; s < NS; s++) add_bf8(g + (size_t)s * (2048 * DM) + (size_t)row * DM + c, v);
  float a = 0.f;
  float4 w0 = *(const float4*)(w3 + c), w1 = *(const float4*)(w3 + c + 4);
  float wv[8] = {w0.x, w0.y, w0.z, w0.w, w1.x, w1.y, w1.z, w1.w};
#pragma unroll
  for (int j = 0; j < 8; j++) {
    float z = 0.5f * v[j] * (1.f + erff(v[j] * 0.70710678118654752f));
    a += z * wv[j];
  }
#pragma unroll
  for (int off = 32; off > 0; off >>= 1) a += __shfl_down(a, off, 64);
  int lane = tid & 63, wid = tid >> 6;
  if (lane == 0) red[wid] = a;
  __syncthreads();
  if (tid == 0) {
    float s = red[0] + red[1] + red[2] + red[3] + b3[0];
    imp[row] = 1.f / (1.f + expf(-s)) + TEMPF;
  }
}

__device__ __forceinline__ float dfun(float cv, int n) {
  float d = fmaxf(cv - (float)n, 0.f);
  if (n < TN - 1) d = fminf(d, 1.f);
  return d;
}

// ---------------- fused cumsum + pool + final ChannelNorm + ReLU, write [B][C][TN] ----
__global__ __launch_bounds__(512) void k_poolfinal(const __hip_bfloat16* __restrict__ f,
                                                   const float* __restrict__ imp,
                                                   const float* __restrict__ gw, const float* __restrict__ gb,
                                                   float* __restrict__ out) {
  __shared__ float wt[T3];
  __shared__ float wsum[8];
  __shared__ float red[16];
  int b = blockIdx.x / TN, n = blockIdx.x % TN;
  int tid = threadIdx.x, wave = tid >> 6, lane = tid & 63;
  float own = imp[b * T3 + tid];
  float s = own;
#pragma unroll
  for (int off = 1; off < 64; off <<= 1) {
    float t = __shfl_up(s, off, 64);
    if (lane >= off) s += t;
  }
  if (lane == 63) wsum[wave] = s;
  __syncthreads();
  float prefix = 0.f, total = 0.f;
#pragma unroll
  for (int w = 0; w < 8; w++) {
    float ws_ = wsum[w];
    total += ws_;
    if (w < wave) prefix += ws_;
  }
  float scale = (float)TN / total;
  float incl = (prefix + s) * scale;
  float excl = (prefix + s - own) * scale;
  wt[tid] = dfun(incl, n) - dfun(excl, n);
  __syncthreads();
  float acc = 0.f;
  for (int t = 0; t < T3; t++) {
    float w = wt[t];
    if (w != 0.f) acc += w * __bfloat162float(f[((size_t)b * T3 + t) * NC + tid]);
  }
  float sv = acc, q = acc * acc;
  blk_sum2_512(sv, q, red);
  float mean = sv * (1.f / NC);
  float var = fmaxf((q - sv * sv * (1.f / NC)) * (1.f / (NC - 1)), 0.f);
  float y = (acc - mean) * rsqrtf(var + EPSF) * gw[tid] + gb[tid];
  out[((size_t)b * NC + tid) * TN + n] = fmaxf(y, 0.f);
}

extern "C" void kernel_launch(void* const* d_in, const int* in_sizes, int n_in,
                              void* d_out, int out_size, void* d_ws, size_t ws_size,
                              hipStream_t stream) {
  const float* x   = (const float*)d_in[0];
  const float* c0w = (const float*)d_in[1];  const float* c0b = (const float*)d_in[2];
  const float* c1w = (const float*)d_in[3];  const float* c1b = (const float*)d_in[4];
  const float* c2w = (const float*)d_in[5];  const float* c2b = (const float*)d_in[6];
  const float* c3w = (const float*)d_in[7];  const float* c3b = (const float*)d_in[8];
  const float* mw1 = (const float*)d_in[9];  const float* mb1 = (const float*)d_in[10];
  const float* mw2 = (const float*)d_in[11]; const float* mb2 = (const float*)d_in[12];
  const float* mw3 = (const float*)d_in[13]; const float* mb3 = (const float*)d_in[14];
  const float* n0w = (const float*)d_in[15]; const float* n0b = (const float*)d_in[16];
  const float* n1w = (const float*)d_in[17]; const float* n1b = (const float*)d_in[18];
  const float* n2w = (const float*)d_in[19]; const float* n2b = (const float*)d_in[20];
  const float* n3w = (const float*)d_in[21]; const float* n3b = (const float*)d_in[22];
  const float* n4w = (const float*)d_in[23]; const float* n4b = (const float*)d_in[24];

  char* base = (char*)d_ws;
  // Workspace map (MiB). Peak 82 MiB (R8 layout).
  __hip_bfloat16* h0b  = (__hip_bfloat16*)(base);                     // [0,32): conv0 out; dead after conv1-gemm
  __hip_bfloat16* h1b  = (__hip_bfloat16*)(base);                     // reuse [0,8)
  __hip_bfloat16* h2b  = (__hip_bfloat16*)(base + (8u << 20));        // reuse [8,12)
  __hip_bfloat16* h3b  = (__hip_bfloat16*)(base + (12u << 20));       // reuse [12,14)
  __hip_bfloat16* z1b  = (__hip_bfloat16*)(base + (14u << 20));       // reuse [14,22)
  float*          imp  = (float*)(base + (22u << 20));                // reuse [22,+8K)
  __hip_bfloat16* g    = (__hip_bfloat16*)(base + (32u << 20));       // [32,64): bf16 split-K partials
  __hip_bfloat16* wm1t = (__hip_bfloat16*)(base + (64u << 20));       // [64,66)
  __hip_bfloat16* wt2  = (__hip_bfloat16*)(base + (66u << 20));       // [66,68)
  __hip_bfloat16* wt3  = (__hip_bfloat16*)(base + (68u << 20));       // [68,70)
  __hip_bfloat16* wt1  = (__hip_bfloat16*)(base + (70u << 20));       // [70,74)
  __hip_bfloat16* wm2t = (__hip_bfloat16*)(base + (74u << 20));       // [74,82)
  float* outp = (float*)d_out;

  k_init<<<4096 + 6656, 512, 0, stream>>>(x, c0w, c0b, n0w, n0b, h0b,
                                          c1w, c2w, c3w, mw1, mw2, wt1, wt2, wt3, wm1t, wm2t);

  // conv1: 256x128, SK4 -> 512 blocks (2/CU) — R11's measured-best conv1 config
  k_gemmA<1, 8192, 2048, 4, 2, 4096, 512, 4, 8192><<<512, 256, 0, stream>>>(h0b, wt1, g);
  k_cnorm<4><<<8192 / 8, 512, 0, stream>>>(g, c1b, n1w, n1b, h1b, (size_t)8192 * 512);
  // conv2: 128x128, SK6 -> 768 blocks (3/CU) — R8 config + strength reduction
  k_gemmB<1, 2048, 1024, 2, 1, 2048, 512, 6, 4096><<<768, 256, 0, stream>>>(h1b, wt2, g);
  k_cnorm<6><<<4096 / 8, 512, 0, stream>>>(g, c2b, n2w, n2b, h2b, (size_t)4096 * 512);
  // conv3: 64x128, SK6 -> 768 blocks
  k_gemmC<1, 1024, 512, 2, 1, 2048, 512, 0, 6, 2048><<<768, 256, 0, stream>>>(h2b, wt3, c3b, g);
  k_cnorm<6><<<2048 / 8, 512, 0, stream>>>(g, c3b, n3w, n3b, h3b, (size_t)2048 * 512);
  // mlp1: 64x128, EPI=GELU -> 512 blocks
  k_gemmC<0, 0, 1, 0, 0, 512, 2048, 1, 1, 2048><<<512, 256, 0, stream>>>(h3b, wm1t, mb1, z1b);
  // mlp2: 128x128, SK3 -> 768 blocks
  k_gemmB<0, 0, 1, 0, 0, 2048, 2048, 3, 2048><<<768, 256, 0, stream>>>(z1b, wm2t, g);

  k_head<3><<<NB * T3, 256, 0, stream>>>(g, mb2, mw3, mb3, imp);
  k_poolfinal<<<NB * TN, 512, 0, stream>>>(h3b, imp, n4w, n4b, outp);
}